// Round 5
// baseline (60559.174 us; speedup 1.0000x reference)
//
#include <hip/hip_runtime.h>
#include <cstdint>
#include <cstddef>

// ============================================================================
// 2-layer GRU (B=512,S=512,C=32,H=512) + projection, MI355X gfx950.
// Persistent kernel, 256 blocks x 256 threads, 2 grid barriers / step.
// Weights split (f16 hi + scaled-lo) persist in LDS.
// r5: ALL cross-phase stores are agent-scope (sc1, write-through to LLC) so
// the per-XCD L2 never holds dirty cross-phase lines => the per-barrier
// release writeback (13.2 GB total in r4, the 55us/phase floor) vanishes.
// Consumers keep normal cached reads (L2 dedup) + one buffer_inv/crossing.
// f32 masters dropped: state carried as f16 hi + scaled-lo (exact to 2^-21).
// ============================================================================

typedef _Float16 f16;
typedef _Float16 half8 __attribute__((ext_vector_type(8)));
typedef float f32x4 __attribute__((ext_vector_type(4)));

#define NT 256
#define NBLK 256
#define SEQ 512
#define SC 2048.0f
#define INV_SC (1.0f / 2048.0f)
#define MFMA16(a, b, c) __builtin_amdgcn_mfma_f32_16x16x32_f16(a, b, c, 0, 0, 0)

// ---- workspace layout (bytes) ----
constexpr size_t OFF_WH0H = 0;                      // 1536x512 f16 each
constexpr size_t OFF_WH0L = 1572864;
constexpr size_t OFF_WI1H = 3145728;
constexpr size_t OFF_WI1L = 4718592;
constexpr size_t OFF_WH1H = 6291456;
constexpr size_t OFF_WH1L = 7864320;
constexpr size_t OFF_WPH  = 9437184;                // 3072x512 f16
constexpr size_t OFF_WI0H = 12582912;               // 1536x32 f16
constexpr size_t OFF_WI0L = 12681216;
// f16 512x512 arrays (0.5 MB each), contiguous zero-init region:
constexpr size_t OFF_H0H  = 12779520;
constexpr size_t OFF_H0L  = 13303808;
constexpr size_t OFF_H1H0 = 13828096;
constexpr size_t OFF_H1L0 = 14352384;
constexpr size_t OFF_H1H1 = 14876672;
constexpr size_t OFF_H1L1 = 15400960;
constexpr size_t OFF_RH0  = 15925248;
constexpr size_t OFF_RH1  = 16449536;
constexpr size_t OFF_Z0   = 16973824;
constexpr size_t OFF_Z1   = 17498112;
constexpr size_t OFF_GIN  = 18022400;               // 512x512 f32
constexpr size_t OFF_BAR  = 19070976;               // 512 uints

// ---- LDS layout (dynamic, 147456 B) ----
constexpr int LO_BA   = 0;        // 64 rows x 1024B, swizzled (phase-A weights)
constexpr int LO_BB   = 65536;    // 32 rows x 1024B, swizzled (phase-B weights)
constexpr int LO_WXA  = 98304;    // 64 rows x 80B (Wi0 rz slice hi/lo)
constexpr int LO_WXB  = 103424;   // 32 rows x 80B (Wi0 n slice hi/lo)
constexpr int LO_STG0 = 106496;   // 20480B staging (pad-80 / pad-144 rows)
constexpr int LO_STG1 = 126976;   // 20480B staging
constexpr int LDS_BYTES = 147456;

__device__ __forceinline__ float sigm(float v) { return 1.f / (1.f + __expf(-v)); }
__device__ __forceinline__ float tanh_f(float v) { float e = __expf(2.f * v); return 1.f - 2.f / (e + 1.f); }
__device__ __forceinline__ void split2(float v, f16& hi, f16& lo) {
  f16 h = (f16)v; hi = h; lo = (f16)((v - (float)h) * SC);
}
// agent-scope (sc1) stores: write through to the device coherence point,
// leaving no dirty line in the per-XCD L2 (so barrier fences stay cheap).
__device__ __forceinline__ void st16(f16* p, f16 v) {
  union { f16 f; unsigned short u; } cv; cv.f = v;
  __hip_atomic_store((unsigned short*)p, cv.u, __ATOMIC_RELAXED, __HIP_MEMORY_SCOPE_AGENT);
}
__device__ __forceinline__ void st32(float* p, float v) {
  __hip_atomic_store(p, v, __ATOMIC_RELAXED, __HIP_MEMORY_SCOPE_AGENT);
}

// ---- one-time weight -> LDS loaders ----
// B regions: row stride 1024B (512 halves), XOR swizzle byte^=((row&7)<<4)
__device__ __forceinline__ void ldB512(char* dst, int row0, const f16* __restrict__ src,
                                       int srcRow0, int nrows, int tid) {
  for (int idx = tid; idx < nrows * 64; idx += NT) {
    int r = idx >> 6, g = idx & 63;
    uint4 v = *(const uint4*)(src + (size_t)(srcRow0 + r) * 512 + g * 8);
    int row = row0 + r;
    *(uint4*)(dst + ((row * 1024 + g * 16) ^ ((row & 7) << 4))) = v;
  }
}
// WX regions: row stride 80B (32 halves data + pad)
__device__ __forceinline__ void ldWX(char* wx, int row0, const f16* __restrict__ src,
                                     int srcRow0, int nrows, int tid) {
  for (int idx = tid; idx < nrows * 4; idx += NT) {
    int r = idx >> 2, g = idx & 3;
    uint4 v = *(const uint4*)(src + (size_t)(srcRow0 + r) * 32 + g * 8);
    *(uint4*)(wx + (row0 + r) * 80 + g * 16) = v;
  }
}

// ---- phase-A driver: 16 chunks (K=32), A rows 256, stride 80, 1 barrier/chunk
template<int FM>
__device__ __forceinline__ void runA(const f16* __restrict__ src, int m0, char* lds,
                                     int wm, int rowH, int rowL,
                                     int tid, int lr, int lkb,
                                     f32x4 (&am)[FM], f32x4 (&ac)[FM]) {
  char* S0 = lds + LO_STG0; char* S1 = lds + LO_STG1;
  const char* BA = lds + LO_BA;
  uint4 rA[4], rB[4];
  auto ld = [&](int c, uint4 (&v)[4]) {
#pragma unroll
    for (int j = 0; j < 4; ++j) { int idx = tid + j * NT; int r = idx >> 2, g = idx & 3;
      v[j] = *(const uint4*)(src + (size_t)(m0 + r) * 512 + c * 32 + g * 8); } };
  auto st = [&](char* S, uint4 (&v)[4]) {
#pragma unroll
    for (int j = 0; j < 4; ++j) { int idx = tid + j * NT; int r = idx >> 2, g = idx & 3;
      *(uint4*)(S + r * 80 + g * 16) = v[j]; } };
  auto mm = [&](const char* S, int c) {
    int rh = rowH + lr, rl = rowL + lr;
    half8 bh = *(const half8*)(BA + ((rh * 1024 + c * 64 + lkb) ^ ((rh & 7) << 4)));
    half8 bl = *(const half8*)(BA + ((rl * 1024 + c * 64 + lkb) ^ ((rl & 7) << 4)));
#pragma unroll
    for (int fm = 0; fm < FM; ++fm) {
      half8 a = *(const half8*)(S + (wm + fm * 16 + lr) * 80 + lkb);
      am[fm] = MFMA16(a, bh, am[fm]); ac[fm] = MFMA16(a, bl, ac[fm]); } };
  ld(0, rA); ld(1, rB); st(S0, rA);
  __syncthreads();
#pragma unroll 1
  for (int c = 0; c < 16; c += 2) {
    if (c + 2 < 16) ld(c + 2, rA);
    mm(S0, c);
    st(S1, rB);
    __syncthreads();
    if (c + 3 < 16) ld(c + 3, rB);
    mm(S1, c + 1);
    if (c + 2 < 16) st(S0, rA);
    __syncthreads();
  }
}

// ---- phase-A dual-source driver (type1): 32 chunks, src/brow switch at 16
__device__ __forceinline__ void runA1(const f16* __restrict__ s0, const f16* __restrict__ s1,
                                      int m0, char* lds, int wm,
                                      int tid, int lr, int lkb,
                                      f32x4 (&am)[4], f32x4 (&ac)[4]) {
  char* S0 = lds + LO_STG0; char* S1 = lds + LO_STG1;
  const char* BA = lds + LO_BA;
  uint4 rA[4], rB[4];
  auto ld = [&](int c, uint4 (&v)[4]) {
    const f16* s = (c < 16) ? s0 : s1; int k0 = (c & 15) * 32;
#pragma unroll
    for (int j = 0; j < 4; ++j) { int idx = tid + j * NT; int r = idx >> 2, g = idx & 3;
      v[j] = *(const uint4*)(s + (size_t)(m0 + r) * 512 + k0 + g * 8); } };
  auto st = [&](char* S, uint4 (&v)[4]) {
#pragma unroll
    for (int j = 0; j < 4; ++j) { int idx = tid + j * NT; int r = idx >> 2, g = idx & 3;
      *(uint4*)(S + r * 80 + g * 16) = v[j]; } };
  auto mm = [&](const char* S, int c) {
    int rb = (c < 16) ? 0 : 32; int kB = (c & 15) * 64;
    int rh = rb + lr, rl = rb + 16 + lr;
    half8 bh = *(const half8*)(BA + ((rh * 1024 + kB + lkb) ^ ((rh & 7) << 4)));
    half8 bl = *(const half8*)(BA + ((rl * 1024 + kB + lkb) ^ ((rl & 7) << 4)));
#pragma unroll
    for (int fm = 0; fm < 4; ++fm) {
      half8 a = *(const half8*)(S + (wm + fm * 16 + lr) * 80 + lkb);
      am[fm] = MFMA16(a, bh, am[fm]); ac[fm] = MFMA16(a, bl, ac[fm]); } };
  ld(0, rA); ld(1, rB); st(S0, rA);
  __syncthreads();
#pragma unroll 1
  for (int c = 0; c < 32; c += 2) {
    if (c + 2 < 32) ld(c + 2, rA);
    mm(S0, c);
    st(S1, rB);
    __syncthreads();
    if (c + 3 < 32) ld(c + 3, rB);
    mm(S1, c + 1);
    if (c + 2 < 32) st(S0, rA);
    __syncthreads();
  }
}

// ---- phase-B driver: 8 chunks (K=64), A rows 128, stride 144
template<int FM>
__device__ __forceinline__ void runB(const f16* __restrict__ src, int m0, char* lds,
                                     int wm, int tid, int lr, int lkb,
                                     f32x4 (&am)[FM], f32x4 (&ac)[FM]) {
  char* S0 = lds + LO_STG0; char* S1 = lds + LO_STG1;
  const char* BB = lds + LO_BB;
  uint4 rA[4], rB[4];
  auto ld = [&](int c, uint4 (&v)[4]) {
#pragma unroll
    for (int j = 0; j < 4; ++j) { int idx = tid + j * NT; int r = idx >> 3, g = idx & 7;
      v[j] = *(const uint4*)(src + (size_t)(m0 + r) * 512 + c * 64 + g * 8); } };
  auto st = [&](char* S, uint4 (&v)[4]) {
#pragma unroll
    for (int j = 0; j < 4; ++j) { int idx = tid + j * NT; int r = idx >> 3, g = idx & 7;
      *(uint4*)(S + r * 144 + g * 16) = v[j]; } };
  auto mm = [&](const char* S, int c) {
#pragma unroll
    for (int ki = 0; ki < 2; ++ki) {
      int rh = lr, rl = 16 + lr;
      half8 bh = *(const half8*)(BB + ((rh * 1024 + c * 128 + ki * 64 + lkb) ^ ((rh & 7) << 4)));
      half8 bl = *(const half8*)(BB + ((rl * 1024 + c * 128 + ki * 64 + lkb) ^ ((rl & 7) << 4)));
#pragma unroll
      for (int fm = 0; fm < FM; ++fm) {
        half8 a = *(const half8*)(S + (wm + fm * 16 + lr) * 144 + ki * 64 + lkb);
        am[fm] = MFMA16(a, bh, am[fm]); ac[fm] = MFMA16(a, bl, ac[fm]); } } };
  ld(0, rA); ld(1, rB); st(S0, rA);
  __syncthreads();
#pragma unroll 1
  for (int c = 0; c < 8; c += 2) {
    if (c + 2 < 8) ld(c + 2, rA);
    mm(S0, c);
    st(S1, rB);
    __syncthreads();
    if (c + 3 < 8) ld(c + 3, rB);
    mm(S1, c + 1);
    if (c + 2 < 8) st(S0, rA);
    __syncthreads();
  }
}

// ---- x-fold: 3-pass split MFMA (xh*Wh -> am; xh*Wl, xl*Wh -> ac), K=32
template<int FM>
__device__ __forceinline__ void mmX(const char* S0, const char* S1, const char* wx,
                                    int wm, int rowH, int rowL, int lr, int lkb,
                                    f32x4 (&am)[FM], f32x4 (&ac)[FM]) {
  half8 bh = *(const half8*)(wx + (rowH + lr) * 80 + lkb);
  half8 bl = *(const half8*)(wx + (rowL + lr) * 80 + lkb);
#pragma unroll
  for (int fm = 0; fm < FM; ++fm) {
    half8 axh = *(const half8*)(S0 + (wm + fm * 16 + lr) * 80 + lkb);
    half8 axl = *(const half8*)(S1 + (wm + fm * 16 + lr) * 80 + lkb);
    am[fm] = MFMA16(axh, bh, am[fm]);
    ac[fm] = MFMA16(axh, bl, ac[fm]);
    ac[fm] = MFMA16(axl, bh, ac[fm]);
  }
}

// two-level monotonic grid barrier (no resets => no ABA).
// RELAXED polls/RMWs; cache maintenance exactly once per crossing via the
// two __threadfence() calls. With all cross-phase stores sc1 (write-through),
// the release-side writeback finds no dirty lines and is cheap.
__device__ __forceinline__ void gbar(unsigned* bar, int bid, unsigned lg) {
  __syncthreads();
  if (threadIdx.x == 0) {
    __threadfence();   // release: order sc1 stores before arrival
    unsigned v = __hip_atomic_fetch_add(bar + ((bid >> 5) << 5), 1u,
                                        __ATOMIC_RELAXED, __HIP_MEMORY_SCOPE_AGENT);
    if (v == lg * 32u - 1u) {
      unsigned r = __hip_atomic_fetch_add(bar + 256, 1u,
                                          __ATOMIC_RELAXED, __HIP_MEMORY_SCOPE_AGENT);
      if (r == lg * 8u - 1u)
        __hip_atomic_store(bar + 288, lg, __ATOMIC_RELAXED, __HIP_MEMORY_SCOPE_AGENT);
    }
    while (__hip_atomic_load(bar + 288, __ATOMIC_RELAXED, __HIP_MEMORY_SCOPE_AGENT) < lg)
      __builtin_amdgcn_s_sleep(2);
    __threadfence();   // acquire: invalidate once, then read fresh
  }
  __syncthreads();
}

// ---------------------------------------------------------------------------
__global__ void gru_setup(const float* __restrict__ Wi0, const float* __restrict__ Wh0,
                          const float* __restrict__ Wi1, const float* __restrict__ Wh1,
                          const float* __restrict__ Wp, char* __restrict__ ws) {
  size_t t = (size_t)blockIdx.x * blockDim.x + threadIdx.x;
  size_t st = (size_t)gridDim.x * blockDim.x;
  f16* wh0h = (f16*)(ws + OFF_WH0H); f16* wh0l = (f16*)(ws + OFF_WH0L);
  f16* wi1h = (f16*)(ws + OFF_WI1H); f16* wi1l = (f16*)(ws + OFF_WI1L);
  f16* wh1h = (f16*)(ws + OFF_WH1H); f16* wh1l = (f16*)(ws + OFF_WH1L);
  f16* wph  = (f16*)(ws + OFF_WPH);
  f16* wi0h = (f16*)(ws + OFF_WI0H); f16* wi0l = (f16*)(ws + OFF_WI0L);
  for (size_t j = t; j < (size_t)1536 * 512; j += st) {
    split2(Wh0[j], wh0h[j], wh0l[j]);
    split2(Wi1[j], wi1h[j], wi1l[j]);
    split2(Wh1[j], wh1h[j], wh1l[j]);
  }
  for (size_t j = t; j < (size_t)3072 * 512; j += st) wph[j] = (f16)Wp[j];
  for (size_t j = t; j < (size_t)1536 * 32; j += st) split2(Wi0[j], wi0h[j], wi0l[j]);
  f16* mir = (f16*)(ws + OFF_H0H);   // 10 contiguous f16 512x512 arrays
  for (size_t j = t; j < (size_t)512 * 512 * 10; j += st) mir[j] = (f16)0.f;
  unsigned* bar = (unsigned*)(ws + OFF_BAR);
  for (size_t j = t; j < 512; j += st) bar[j] = 0u;
}

// ---------------------------------------------------------------------------
__global__ __launch_bounds__(NT, 1) void gru_main(
    const float* __restrict__ x, const float* __restrict__ b0, const float* __restrict__ b1,
    const float* __restrict__ bp, float* __restrict__ out, char* __restrict__ ws)
{
  extern __shared__ char lds[];

  const f16* WH0Hp = (const f16*)(ws + OFF_WH0H); const f16* WH0Lp = (const f16*)(ws + OFF_WH0L);
  const f16* WI1Hp = (const f16*)(ws + OFF_WI1H); const f16* WI1Lp = (const f16*)(ws + OFF_WI1L);
  const f16* WH1Hp = (const f16*)(ws + OFF_WH1H); const f16* WH1Lp = (const f16*)(ws + OFF_WH1L);
  const f16* WPHp  = (const f16*)(ws + OFF_WPH);
  const f16* WI0Hp = (const f16*)(ws + OFF_WI0H); const f16* WI0Lp = (const f16*)(ws + OFF_WI0L);
  f16* H0H = (f16*)(ws + OFF_H0H);
  f16* H0L = (f16*)(ws + OFF_H0L);
  f16* RH0 = (f16*)(ws + OFF_RH0);
  f16* RH1 = (f16*)(ws + OFF_RH1);
  f16* Z0  = (f16*)(ws + OFF_Z0);
  f16* Z1  = (f16*)(ws + OFF_Z1);
  float* GIN = (float*)(ws + OFF_GIN);
  unsigned* bar = (unsigned*)(ws + OFF_BAR);

  const int bid = blockIdx.x, tid = threadIdx.x;
  const int wid = tid >> 6, lane = tid & 63;
  const int lr = lane & 15, lh = lane >> 4, lkb = lh << 4;
  const int xcd = bid & 7, kk = bid >> 3;

  // phase-A role (XCD-grouped): aid = xcd*28 + kk, kk<28
  const bool hasA = kk < 28;
  const int aid = xcd * 28 + kk;
  const int mgA = hasA ? aid / 112 : 0;
  const int sA = hasA ? aid % 112 : 0;
  const int typeA = sA < 32 ? 0 : (sA < 96 ? 1 : 2);
  const int slotA = typeA == 0 ? sA : (typeA == 1 ? sA - 32 : sA - 96);
  const int m0A = mgA * 256;
  const int wm02 = (wid >> 1) * 128, wn02 = (wid & 1) * 16;
  const int wm1 = wid * 64;

  // phase-B role: pb = xcd*32 + kk
  const int pb = xcd * 32 + kk;
  const int mgB = pb >> 6, sB = pb & 63;
  const bool isN0 = sB < 32;
  const int colB0 = (sB & 31) * 16;
  const int m0B = mgB * 128, wmB = wid * 32;

  char* BA = lds + LO_BA; char* BB = lds + LO_BB;
  char* WXA = lds + LO_WXA; char* WXB = lds + LO_WXB;
  char* S0 = lds + LO_STG0; char* S1 = lds + LO_STG1;

  // ---- one-time: weights -> LDS (persistent across all barriers) ----
  if (hasA) {
    if (typeA == 0) {
      ldB512(BA, 0, WH0Hp, slotA * 32, 32, tid); ldB512(BA, 32, WH0Lp, slotA * 32, 32, tid);
      ldWX(WXA, 0, WI0Hp, slotA * 32, 32, tid);  ldWX(WXA, 32, WI0Lp, slotA * 32, 32, tid);
    } else if (typeA == 1) {
      ldB512(BA, 0, WI1Hp, slotA * 16, 16, tid); ldB512(BA, 16, WI1Lp, slotA * 16, 16, tid);
      ldB512(BA, 32, WH1Hp, slotA * 16, 16, tid); ldB512(BA, 48, WH1Lp, slotA * 16, 16, tid);
    } else {
      ldB512(BA, 0, WI1Hp, 1024 + slotA * 32, 32, tid); ldB512(BA, 32, WI1Lp, 1024 + slotA * 32, 32, tid);
    }
  }
  if (isN0) {
    ldB512(BB, 0, WH0Hp, 1024 + colB0, 16, tid); ldB512(BB, 16, WH0Lp, 1024 + colB0, 16, tid);
    ldWX(WXB, 0, WI0Hp, 1024 + colB0, 16, tid);  ldWX(WXB, 16, WI0Lp, 1024 + colB0, 16, tid);
  } else {
    ldB512(BB, 0, WH1Hp, 1024 + colB0, 16, tid); ldB512(BB, 16, WH1Lp, 1024 + colB0, 16, tid);
  }
  __syncthreads();

  // per-thread constant biases
  float biasA = 0.f;
  if (hasA) {
    if (typeA == 0)      biasA = b0[slotA * 32 + wn02 + lr];
    else if (typeA == 1) biasA = b1[slotA * 16 + lr];
    else                 biasA = b1[1024 + slotA * 32 + wn02 + lr];
  }
  const float biasB = isN0 ? b0[1024 + colB0 + lr] : 0.f;

  unsigned lg = 0;
  for (int i = 0; i <= SEQ; ++i) {
    const int wpar = i & 1;  // H1 write parity this iter; read = opposite
    const f16* H1Hr = (const f16*)(ws + (wpar ? OFF_H1H0 : OFF_H1H1));
    const f16* H1Lr = (const f16*)(ws + (wpar ? OFF_H1L0 : OFF_H1L1));
    f16* H1Hw = (f16*)(ws + (wpar ? OFF_H1H1 : OFF_H1H0));
    f16* H1Lw = (f16*)(ws + (wpar ? OFF_H1L1 : OFF_H1L0));

    // ========================= PHASE A =========================
    if (hasA) {
      if (typeA == 0 && i < SEQ) {
        // preload x slice (hidden under GEMM)
        float4 xr[8];
#pragma unroll
        for (int j = 0; j < 4; ++j) { int idx = tid + j * NT; int r = idx >> 2, g = idx & 3;
          const float* sx = x + (((size_t)(m0A + r)) << 14) + (size_t)i * 32 + g * 8;
          xr[2 * j] = ((const float4*)sx)[0]; xr[2 * j + 1] = ((const float4*)sx)[1]; }
        f32x4 am[8] = {}, ac[8] = {};
        runA<8>(H0H, m0A, lds, wm02, wn02, 32 + wn02, tid, lr, lkb, am, ac);
        // x-fold (K=32, split)
#pragma unroll
        for (int j = 0; j < 4; ++j) { int idx = tid + j * NT; int r = idx >> 2, g = idx & 3;
          union { uint4 u; f16 e[8]; } H, L;
          const float* f0 = (const float*)&xr[2 * j];
          const float* f1 = (const float*)&xr[2 * j + 1];
#pragma unroll
          for (int e = 0; e < 4; ++e) { split2(f0[e], H.e[e], L.e[e]); split2(f1[e], H.e[4 + e], L.e[4 + e]); }
          *(uint4*)(S0 + r * 80 + g * 16) = H.u; *(uint4*)(S1 + r * 80 + g * 16) = L.u; }
        __syncthreads();
        mmX<8>(S0, S1, WXA, wm02, wn02, 32 + wn02, lr, lkb, am, ac);
        // epilogue: r/z gates
        const bool isR = (slotA < 16);
        const int ncol = slotA * 32 + wn02 + lr;
        size_t base = (size_t)(m0A + wm02 + lh * 4) * 512 + ncol;
#pragma unroll
        for (int fm = 0; fm < 8; ++fm)
#pragma unroll
        for (int r4 = 0; r4 < 4; ++r4) {
          size_t off = base + (size_t)(fm * 16 + r4) * 512;
          float s = sigm(am[fm][r4] + ac[fm][r4] * INV_SC + biasA);
          if (isR) {
            float h0v = (float)H0H[off] + (float)H0L[off] * INV_SC;
            st16(RH0 + off, (f16)(s * h0v));
          } else {
            st16(Z0 + off - 512, (f16)s);
          }
        }
      } else if (typeA == 1 && i >= 1) {
        f32x4 am[4] = {}, ac[4] = {};
        runA1(H0H, H1Hr, m0A, lds, wm1, tid, lr, lkb, am, ac);
        const bool isR = (slotA < 32);
        const int ncol = slotA * 16 + lr;
        size_t base = (size_t)(m0A + wm1 + lh * 4) * 512 + ncol;
#pragma unroll
        for (int fm = 0; fm < 4; ++fm)
#pragma unroll
        for (int r4 = 0; r4 < 4; ++r4) {
          size_t off = base + (size_t)(fm * 16 + r4) * 512;
          float s = sigm(am[fm][r4] + ac[fm][r4] * INV_SC + biasA);
          if (isR) {
            float h1v = (float)H1Hr[off] + (float)H1Lr[off] * INV_SC;
            st16(RH1 + off, (f16)(s * h1v));
          } else {
            st16(Z1 + off - 512, (f16)s);
          }
        }
      } else if (typeA == 2 && i >= 1) {
        f32x4 am[8] = {}, ac[8] = {};
        runA<8>(H0H, m0A, lds, wm02, wn02, 32 + wn02, tid, lr, lkb, am, ac);
        const int ncol = slotA * 32 + wn02 + lr;
        size_t base = (size_t)(m0A + wm02 + lh * 4) * 512 + ncol;
#pragma unroll
        for (int fm = 0; fm < 8; ++fm)
#pragma unroll
        for (int r4 = 0; r4 < 4; ++r4) {
          size_t off = base + (size_t)(fm * 16 + r4) * 512;
          st32(GIN + off, am[fm][r4] + ac[fm][r4] * INV_SC + biasA);
        }
      }
    }
    ++lg; gbar(bar, bid, lg);

    // ========================= PHASE B =========================
    if (isN0 ? (i < SEQ) : (i >= 1)) {
      f32x4 am[2] = {}, ac[2] = {};
      if (isN0) {
        float4 xr[4];
#pragma unroll
        for (int j = 0; j < 2; ++j) { int idx = tid + j * NT; int r = idx >> 2, g = idx & 3;
          const float* sx = x + (((size_t)(m0B + r)) << 14) + (size_t)i * 32 + g * 8;
          xr[2 * j] = ((const float4*)sx)[0]; xr[2 * j + 1] = ((const float4*)sx)[1]; }
        runB<2>(RH0, m0B, lds, wmB, tid, lr, lkb, am, ac);
#pragma unroll
        for (int j = 0; j < 2; ++j) { int idx = tid + j * NT; int r = idx >> 2, g = idx & 3;
          union { uint4 u; f16 e[8]; } H, L;
          const float* f0 = (const float*)&xr[2 * j];
          const float* f1 = (const float*)&xr[2 * j + 1];
#pragma unroll
          for (int e = 0; e < 4; ++e) { split2(f0[e], H.e[e], L.e[e]); split2(f1[e], H.e[4 + e], L.e[4 + e]); }
          *(uint4*)(S0 + r * 80 + g * 16) = H.u; *(uint4*)(S1 + r * 80 + g * 16) = L.u; }
        __syncthreads();
        mmX<2>(S0, S1, WXB, wmB, 0, 16, lr, lkb, am, ac);
        size_t base = (size_t)(m0B + wmB + lh * 4) * 512 + colB0 + lr;
#pragma unroll
        for (int fm = 0; fm < 2; ++fm)
#pragma unroll
        for (int r4 = 0; r4 < 4; ++r4) {
          size_t off = base + (size_t)(fm * 16 + r4) * 512;
          float nv = tanh_f(am[fm][r4] + ac[fm][r4] * INV_SC + biasB);
          float z = (float)Z0[off];
          float h0v = (float)H0H[off] + (float)H0L[off] * INV_SC;
          float hn = (1.f - z) * nv + z * h0v;
          f16 hi, lo; split2(hn, hi, lo);
          st16(H0H + off, hi); st16(H0L + off, lo);
        }
      } else {
        runB<2>(RH1, m0B, lds, wmB, tid, lr, lkb, am, ac);
        size_t base = (size_t)(m0B + wmB + lh * 4) * 512 + colB0 + lr;
#pragma unroll
        for (int fm = 0; fm < 2; ++fm)
#pragma unroll
        for (int r4 = 0; r4 < 4; ++r4) {
          size_t off = base + (size_t)(fm * 16 + r4) * 512;
          float nv = tanh_f(am[fm][r4] + ac[fm][r4] * INV_SC + GIN[off]);
          float z = (float)Z1[off];
          float h1v = (float)H1Hr[off] + (float)H1Lr[off] * INV_SC;
          float hn = (1.f - z) * nv + z * h1v;
          f16 hi, lo; split2(hn, hi, lo);
          st16(H1Hw + off, hi); st16(H1Lw + off, lo);
        }
      }
    }
    ++lg; gbar(bar, bid, lg);
  }

  // ========================= PROJECTION (single f16) =========================
  {
    const f16* H1p = (const f16*)(ws + OFF_H1H0);   // final h1 (written at i=512, parity 0)
    const int m0 = (bid >> 6) * 128, col0 = (bid & 63) * 48;
    const int wm = wid * 32;
    f32x4 acc[2][3] = {};
#pragma unroll 1
    for (int c = 0; c < 8; ++c) {
      uint4 va[4]; uint4 vb[2];
#pragma unroll
      for (int j = 0; j < 4; ++j) { int idx = tid + j * NT; int r = idx >> 3, g = idx & 7;
        va[j] = *(const uint4*)(H1p + (size_t)(m0 + r) * 512 + c * 64 + g * 8); }
#pragma unroll
      for (int j = 0; j < 2; ++j) { int idx = tid + j * NT;
        if (idx < 384) { int r = idx >> 3, g = idx & 7;
          vb[j] = *(const uint4*)(WPHp + (size_t)(col0 + r) * 512 + c * 64 + g * 8); } }
      __syncthreads();   // prev mfma done reading staging
#pragma unroll
      for (int j = 0; j < 4; ++j) { int idx = tid + j * NT; int r = idx >> 3, g = idx & 7;
        *(uint4*)(S0 + r * 144 + g * 16) = va[j]; }
#pragma unroll
      for (int j = 0; j < 2; ++j) { int idx = tid + j * NT;
        if (idx < 384) { int r = idx >> 3, g = idx & 7;
          *(uint4*)(S1 + r * 144 + g * 16) = vb[j]; } }
      __syncthreads();
#pragma unroll
      for (int ki = 0; ki < 2; ++ki) {
        half8 b[3];
#pragma unroll
        for (int fn = 0; fn < 3; ++fn)
          b[fn] = *(const half8*)(S1 + (fn * 16 + lr) * 144 + ki * 64 + lkb);
#pragma unroll
        for (int fm = 0; fm < 2; ++fm) {
          half8 a = *(const half8*)(S0 + (wm + fm * 16 + lr) * 144 + ki * 64 + lkb);
#pragma unroll
          for (int fn = 0; fn < 3; ++fn) acc[fm][fn] = MFMA16(a, b[fn], acc[fm][fn]);
        }
      }
    }
#pragma unroll
    for (int fm = 0; fm < 2; ++fm)
#pragma unroll
    for (int fn = 0; fn < 3; ++fn)
#pragma unroll
    for (int r4 = 0; r4 < 4; ++r4) {
      int m = m0 + wm + fm * 16 + lh * 4 + r4;
      int nc = col0 + fn * 16 + lr;
      out[(size_t)m * 3072 + nc] = acc[fm][fn][r4] + bp[nc];
    }
  }
}

// ---------------------------------------------------------------------------
extern "C" void kernel_launch(void* const* d_in, const int* in_sizes, int n_in,
                              void* d_out, int out_size, void* d_ws, size_t ws_size,
                              hipStream_t stream) {
  (void)in_sizes; (void)n_in; (void)out_size; (void)ws_size; // needs ws >= ~19.1MB
  const float* x   = (const float*)d_in[0];
  const float* Wi0 = (const float*)d_in[1];
  const float* Wh0 = (const float*)d_in[2];
  const float* b0  = (const float*)d_in[3];
  const float* Wi1 = (const float*)d_in[4];
  const float* Wh1 = (const float*)d_in[5];
  const float* b1  = (const float*)d_in[6];
  const float* Wp  = (const float*)d_in[7];
  const float* bp  = (const float*)d_in[8];
  char* ws = (char*)d_ws;
  static_assert(LDS_BYTES <= 163840, "LDS budget");
  (void)hipFuncSetAttribute(reinterpret_cast<const void*>(gru_main),
                            hipFuncAttributeMaxDynamicSharedMemorySize, LDS_BYTES);
  hipLaunchKernelGGL(gru_setup, dim3(512), dim3(NT), 0, stream, Wi0, Wh0, Wi1, Wh1, Wp, ws);
  hipLaunchKernelGGL(gru_main, dim3(NBLK), dim3(NT), LDS_BYTES, stream,
                     x, b0, b1, bp, (float*)d_out, ws);
}

// Round 6
// 32781.580 us; speedup vs baseline: 1.8474x; 1.8474x over previous
//
#include <hip/hip_runtime.h>
#include <cstdint>
#include <cstddef>

// ============================================================================
// 2-layer GRU (B=512,S=512,C=32,H=512) + projection, MI355X gfx950.
// Persistent kernel, 256 blocks x 256 threads, 2 grid barriers / step.
// Weights split (f16 hi + scaled-lo) persist in LDS.
// r6: cross-phase data moves ENTIRELY through agent-scope (sc1) stores AND
// loads => no stale-L2 possibility => no buffer_inv per crossing. Barrier is
// store-arrival + parallel master poll + replicated release flags (no RMW
// contention, no acquire fence). Staging loads pipelined 4 chunks deep to
// cover LLC (~600-900ns) latency.
// ============================================================================

typedef _Float16 f16;
typedef _Float16 half8 __attribute__((ext_vector_type(8)));
typedef float f32x4 __attribute__((ext_vector_type(4)));
typedef unsigned long long u64;

#define NT 256
#define NBLK 256
#define SEQ 512
#define SC 2048.0f
#define INV_SC (1.0f / 2048.0f)
#define MFMA16(a, b, c) __builtin_amdgcn_mfma_f32_16x16x32_f16(a, b, c, 0, 0, 0)

// ---- workspace layout (bytes) ----
constexpr size_t OFF_WH0H = 0;                      // 1536x512 f16 each
constexpr size_t OFF_WH0L = 1572864;
constexpr size_t OFF_WI1H = 3145728;
constexpr size_t OFF_WI1L = 4718592;
constexpr size_t OFF_WH1H = 6291456;
constexpr size_t OFF_WH1L = 7864320;
constexpr size_t OFF_WPH  = 9437184;                // 3072x512 f16
constexpr size_t OFF_WI0H = 12582912;               // 1536x32 f16
constexpr size_t OFF_WI0L = 12681216;
// f16 512x512 arrays (0.5 MB each), contiguous zero-init region:
constexpr size_t OFF_H0H  = 12779520;
constexpr size_t OFF_H0L  = 13303808;
constexpr size_t OFF_H1H0 = 13828096;
constexpr size_t OFF_H1L0 = 14352384;
constexpr size_t OFF_H1H1 = 14876672;
constexpr size_t OFF_H1L1 = 15400960;
constexpr size_t OFF_RH0  = 15925248;
constexpr size_t OFF_RH1  = 16449536;
constexpr size_t OFF_Z0   = 16973824;
constexpr size_t OFF_Z1   = 17498112;
constexpr size_t OFF_GIN  = 18022400;               // 512x512 f32
constexpr size_t OFF_BAR  = 19070976;               // 32KB barrier region

// ---- LDS layout (dynamic, 147456 B) ----
constexpr int LO_BA   = 0;        // 64 rows x 1024B, swizzled (phase-A weights)
constexpr int LO_BB   = 65536;    // 32 rows x 1024B, swizzled (phase-B weights)
constexpr int LO_WXA  = 98304;    // 64 rows x 80B (Wi0 rz slice hi/lo)
constexpr int LO_WXB  = 103424;   // 32 rows x 80B (Wi0 n slice hi/lo)
constexpr int LO_STG0 = 106496;   // 20480B staging (pad-80 / pad-144 rows)
constexpr int LO_STG1 = 126976;   // 20480B staging
constexpr int LDS_BYTES = 147456;

__device__ __forceinline__ float sigm(float v) { return 1.f / (1.f + __expf(-v)); }
__device__ __forceinline__ float tanh_f(float v) { float e = __expf(2.f * v); return 1.f - 2.f / (e + 1.f); }
__device__ __forceinline__ void split2(float v, f16& hi, f16& lo) {
  f16 h = (f16)v; hi = h; lo = (f16)((v - (float)h) * SC);
}
// agent-scope (sc1) accessors: bypass/write-through the per-XCD L2, so
// cross-phase data never has a stale L2 copy and needs no inv.
__device__ __forceinline__ void st16(f16* p, f16 v) {
  union { f16 f; unsigned short u; } cv; cv.f = v;
  __hip_atomic_store((unsigned short*)p, cv.u, __ATOMIC_RELAXED, __HIP_MEMORY_SCOPE_AGENT);
}
__device__ __forceinline__ void st32(float* p, float v) {
  __hip_atomic_store(p, v, __ATOMIC_RELAXED, __HIP_MEMORY_SCOPE_AGENT);
}
__device__ __forceinline__ float ld16f(const f16* p) {
  unsigned short u = __hip_atomic_load((const unsigned short*)p, __ATOMIC_RELAXED, __HIP_MEMORY_SCOPE_AGENT);
  union { unsigned short u; f16 f; } cv; cv.u = u; return (float)cv.f;
}
__device__ __forceinline__ float ld32f(const float* p) {
  return __hip_atomic_load(p, __ATOMIC_RELAXED, __HIP_MEMORY_SCOPE_AGENT);
}
__device__ __forceinline__ void ld16a(const f16* p, uint4& v) {
  const u64* q = (const u64*)p;
  u64 a = __hip_atomic_load(q,     __ATOMIC_RELAXED, __HIP_MEMORY_SCOPE_AGENT);
  u64 b = __hip_atomic_load(q + 1, __ATOMIC_RELAXED, __HIP_MEMORY_SCOPE_AGENT);
  v.x = (unsigned)a; v.y = (unsigned)(a >> 32);
  v.z = (unsigned)b; v.w = (unsigned)(b >> 32);
}

// ---- one-time weight -> LDS loaders ----
__device__ __forceinline__ void ldB512(char* dst, int row0, const f16* __restrict__ src,
                                       int srcRow0, int nrows, int tid) {
  for (int idx = tid; idx < nrows * 64; idx += NT) {
    int r = idx >> 6, g = idx & 63;
    uint4 v = *(const uint4*)(src + (size_t)(srcRow0 + r) * 512 + g * 8);
    int row = row0 + r;
    *(uint4*)(dst + ((row * 1024 + g * 16) ^ ((row & 7) << 4))) = v;
  }
}
__device__ __forceinline__ void ldWX(char* wx, int row0, const f16* __restrict__ src,
                                     int srcRow0, int nrows, int tid) {
  for (int idx = tid; idx < nrows * 4; idx += NT) {
    int r = idx >> 2, g = idx & 3;
    uint4 v = *(const uint4*)(src + (size_t)(srcRow0 + r) * 32 + g * 8);
    *(uint4*)(wx + (row0 + r) * 80 + g * 16) = v;
  }
}

// ---- phase-A driver: 16 chunks (K=32), A rows 256, stride 80, depth-4 pipe
template<int FM>
__device__ __forceinline__ void runA(const f16* __restrict__ src, int m0, char* lds,
                                     int wm, int rowH, int rowL,
                                     int tid, int lr, int lkb,
                                     f32x4 (&am)[FM], f32x4 (&ac)[FM]) {
  char* S0 = lds + LO_STG0; char* S1 = lds + LO_STG1;
  const char* BA = lds + LO_BA;
  uint4 r0[4], r1[4], r2[4], r3[4];
  auto ld = [&](int c, uint4 (&v)[4]) {
#pragma unroll
    for (int j = 0; j < 4; ++j) { int idx = tid + j * NT; int r = idx >> 2, g = idx & 3;
      ld16a(src + (size_t)(m0 + r) * 512 + c * 32 + g * 8, v[j]); } };
  auto st = [&](char* S, uint4 (&v)[4]) {
#pragma unroll
    for (int j = 0; j < 4; ++j) { int idx = tid + j * NT; int r = idx >> 2, g = idx & 3;
      *(uint4*)(S + r * 80 + g * 16) = v[j]; } };
  auto mm = [&](const char* S, int c) {
    int rh = rowH + lr, rl = rowL + lr;
    half8 bh = *(const half8*)(BA + ((rh * 1024 + c * 64 + lkb) ^ ((rh & 7) << 4)));
    half8 bl = *(const half8*)(BA + ((rl * 1024 + c * 64 + lkb) ^ ((rl & 7) << 4)));
#pragma unroll
    for (int fm = 0; fm < FM; ++fm) {
      half8 a = *(const half8*)(S + (wm + fm * 16 + lr) * 80 + lkb);
      am[fm] = MFMA16(a, bh, am[fm]); ac[fm] = MFMA16(a, bl, ac[fm]); } };
  ld(0, r0); ld(1, r1); ld(2, r2); ld(3, r3);
  st(S0, r0);
  __syncthreads();
#pragma unroll 1
  for (int c0 = 0; c0 < 16; c0 += 4) {
    if (c0 + 4 < 16) ld(c0 + 4, r0);
    mm(S0, c0);     st(S1, r1); __syncthreads();
    if (c0 + 5 < 16) ld(c0 + 5, r1);
    mm(S1, c0 + 1); st(S0, r2); __syncthreads();
    if (c0 + 6 < 16) ld(c0 + 6, r2);
    mm(S0, c0 + 2); st(S1, r3); __syncthreads();
    if (c0 + 7 < 16) ld(c0 + 7, r3);
    mm(S1, c0 + 3); st(S0, r0); __syncthreads();
  }
}

// ---- phase-A dual-source driver (type1): 32 chunks, src/brow switch at 16
__device__ __forceinline__ void runA1(const f16* __restrict__ s0p, const f16* __restrict__ s1p,
                                      int m0, char* lds, int wm,
                                      int tid, int lr, int lkb,
                                      f32x4 (&am)[4], f32x4 (&ac)[4]) {
  char* S0 = lds + LO_STG0; char* S1 = lds + LO_STG1;
  const char* BA = lds + LO_BA;
  uint4 r0[4], r1[4], r2[4], r3[4];
  auto ld = [&](int c, uint4 (&v)[4]) {
    const f16* s = (c < 16) ? s0p : s1p; int k0 = (c & 15) * 32;
#pragma unroll
    for (int j = 0; j < 4; ++j) { int idx = tid + j * NT; int r = idx >> 2, g = idx & 3;
      ld16a(s + (size_t)(m0 + r) * 512 + k0 + g * 8, v[j]); } };
  auto st = [&](char* S, uint4 (&v)[4]) {
#pragma unroll
    for (int j = 0; j < 4; ++j) { int idx = tid + j * NT; int r = idx >> 2, g = idx & 3;
      *(uint4*)(S + r * 80 + g * 16) = v[j]; } };
  auto mm = [&](const char* S, int c) {
    int rb = (c < 16) ? 0 : 32; int kB = (c & 15) * 64;
    int rh = rb + lr, rl = rb + 16 + lr;
    half8 bh = *(const half8*)(BA + ((rh * 1024 + kB + lkb) ^ ((rh & 7) << 4)));
    half8 bl = *(const half8*)(BA + ((rl * 1024 + kB + lkb) ^ ((rl & 7) << 4)));
#pragma unroll
    for (int fm = 0; fm < 4; ++fm) {
      half8 a = *(const half8*)(S + (wm + fm * 16 + lr) * 80 + lkb);
      am[fm] = MFMA16(a, bh, am[fm]); ac[fm] = MFMA16(a, bl, ac[fm]); } };
  ld(0, r0); ld(1, r1); ld(2, r2); ld(3, r3);
  st(S0, r0);
  __syncthreads();
#pragma unroll 1
  for (int c0 = 0; c0 < 32; c0 += 4) {
    if (c0 + 4 < 32) ld(c0 + 4, r0);
    mm(S0, c0);     st(S1, r1); __syncthreads();
    if (c0 + 5 < 32) ld(c0 + 5, r1);
    mm(S1, c0 + 1); st(S0, r2); __syncthreads();
    if (c0 + 6 < 32) ld(c0 + 6, r2);
    mm(S0, c0 + 2); st(S1, r3); __syncthreads();
    if (c0 + 7 < 32) ld(c0 + 7, r3);
    mm(S1, c0 + 3); st(S0, r0); __syncthreads();
  }
}

// ---- phase-B driver: 8 chunks (K=64), A rows 128, stride 144, depth-4 pipe
template<int FM>
__device__ __forceinline__ void runB(const f16* __restrict__ src, int m0, char* lds,
                                     int wm, int tid, int lr, int lkb,
                                     f32x4 (&am)[FM], f32x4 (&ac)[FM]) {
  char* S0 = lds + LO_STG0; char* S1 = lds + LO_STG1;
  const char* BB = lds + LO_BB;
  uint4 r0[4], r1[4], r2[4], r3[4];
  auto ld = [&](int c, uint4 (&v)[4]) {
#pragma unroll
    for (int j = 0; j < 4; ++j) { int idx = tid + j * NT; int r = idx >> 3, g = idx & 7;
      ld16a(src + (size_t)(m0 + r) * 512 + c * 64 + g * 8, v[j]); } };
  auto st = [&](char* S, uint4 (&v)[4]) {
#pragma unroll
    for (int j = 0; j < 4; ++j) { int idx = tid + j * NT; int r = idx >> 3, g = idx & 7;
      *(uint4*)(S + r * 144 + g * 16) = v[j]; } };
  auto mm = [&](const char* S, int c) {
#pragma unroll
    for (int ki = 0; ki < 2; ++ki) {
      int rh = lr, rl = 16 + lr;
      half8 bh = *(const half8*)(BB + ((rh * 1024 + c * 128 + ki * 64 + lkb) ^ ((rh & 7) << 4)));
      half8 bl = *(const half8*)(BB + ((rl * 1024 + c * 128 + ki * 64 + lkb) ^ ((rl & 7) << 4)));
#pragma unroll
      for (int fm = 0; fm < FM; ++fm) {
        half8 a = *(const half8*)(S + (wm + fm * 16 + lr) * 144 + ki * 64 + lkb);
        am[fm] = MFMA16(a, bh, am[fm]); ac[fm] = MFMA16(a, bl, ac[fm]); } } };
  ld(0, r0); ld(1, r1); ld(2, r2); ld(3, r3);
  st(S0, r0);
  __syncthreads();
#pragma unroll 1
  for (int c0 = 0; c0 < 8; c0 += 4) {
    if (c0 + 4 < 8) ld(c0 + 4, r0);
    mm(S0, c0);     st(S1, r1); __syncthreads();
    if (c0 + 5 < 8) ld(c0 + 5, r1);
    mm(S1, c0 + 1); st(S0, r2); __syncthreads();
    if (c0 + 6 < 8) ld(c0 + 6, r2);
    mm(S0, c0 + 2); st(S1, r3); __syncthreads();
    if (c0 + 7 < 8) ld(c0 + 7, r3);
    mm(S1, c0 + 3); st(S0, r0); __syncthreads();
  }
}

// ---- x-fold: 3-pass split MFMA (xh*Wh -> am; xh*Wl, xl*Wh -> ac), K=32
template<int FM>
__device__ __forceinline__ void mmX(const char* S0, const char* S1, const char* wx,
                                    int wm, int rowH, int rowL, int lr, int lkb,
                                    f32x4 (&am)[FM], f32x4 (&ac)[FM]) {
  half8 bh = *(const half8*)(wx + (rowH + lr) * 80 + lkb);
  half8 bl = *(const half8*)(wx + (rowL + lr) * 80 + lkb);
#pragma unroll
  for (int fm = 0; fm < FM; ++fm) {
    half8 axh = *(const half8*)(S0 + (wm + fm * 16 + lr) * 80 + lkb);
    half8 axl = *(const half8*)(S1 + (wm + fm * 16 + lr) * 80 + lkb);
    am[fm] = MFMA16(axh, bh, am[fm]);
    ac[fm] = MFMA16(axh, bl, ac[fm]);
    ac[fm] = MFMA16(axl, bh, ac[fm]);
  }
}

// Store-arrival grid barrier (monotonic generations, no resets => no ABA).
// - arrival: one relaxed sc1 STORE per block into its own 64B slot (no RMWs)
// - master (block 0): 255 threads poll the 255 slots in parallel, then
//   replicate the release flag into 16 lines (<=16 pollers per line)
// - release fence only (wbl2 on a clean L2, cheap); NO invalidate: all
//   cross-phase data moves via sc1 loads/stores, so no stale L2 copy exists.
__device__ __forceinline__ void gbar(unsigned* bar, int bid, int tid, unsigned lg) {
  __syncthreads();   // all data stores vmcnt-acked at the coherence point
  if (bid == 0) {
    if (tid == 0) {
      __threadfence();
    } else {
      while (__hip_atomic_load(bar + tid * 16, __ATOMIC_RELAXED, __HIP_MEMORY_SCOPE_AGENT) < lg)
        __builtin_amdgcn_s_sleep(1);
    }
    __syncthreads();  // fence done + all slots seen
    if (tid < 16)
      __hip_atomic_store(bar + 4096 + tid * 16, lg, __ATOMIC_RELAXED, __HIP_MEMORY_SCOPE_AGENT);
  } else if (tid == 0) {
    __threadfence();
    __hip_atomic_store(bar + bid * 16, lg, __ATOMIC_RELAXED, __HIP_MEMORY_SCOPE_AGENT);
  }
  if (tid == 0) {
    while (__hip_atomic_load(bar + 4096 + (bid & 15) * 16, __ATOMIC_RELAXED, __HIP_MEMORY_SCOPE_AGENT) < lg)
      __builtin_amdgcn_s_sleep(1);
  }
  __syncthreads();
}

// ---------------------------------------------------------------------------
__global__ void gru_setup(const float* __restrict__ Wi0, const float* __restrict__ Wh0,
                          const float* __restrict__ Wi1, const float* __restrict__ Wh1,
                          const float* __restrict__ Wp, char* __restrict__ ws) {
  size_t t = (size_t)blockIdx.x * blockDim.x + threadIdx.x;
  size_t st = (size_t)gridDim.x * blockDim.x;
  f16* wh0h = (f16*)(ws + OFF_WH0H); f16* wh0l = (f16*)(ws + OFF_WH0L);
  f16* wi1h = (f16*)(ws + OFF_WI1H); f16* wi1l = (f16*)(ws + OFF_WI1L);
  f16* wh1h = (f16*)(ws + OFF_WH1H); f16* wh1l = (f16*)(ws + OFF_WH1L);
  f16* wph  = (f16*)(ws + OFF_WPH);
  f16* wi0h = (f16*)(ws + OFF_WI0H); f16* wi0l = (f16*)(ws + OFF_WI0L);
  for (size_t j = t; j < (size_t)1536 * 512; j += st) {
    split2(Wh0[j], wh0h[j], wh0l[j]);
    split2(Wi1[j], wi1h[j], wi1l[j]);
    split2(Wh1[j], wh1h[j], wh1l[j]);
  }
  for (size_t j = t; j < (size_t)3072 * 512; j += st) wph[j] = (f16)Wp[j];
  for (size_t j = t; j < (size_t)1536 * 32; j += st) split2(Wi0[j], wi0h[j], wi0l[j]);
  f16* mir = (f16*)(ws + OFF_H0H);   // 10 contiguous f16 512x512 arrays
  for (size_t j = t; j < (size_t)512 * 512 * 10; j += st) mir[j] = (f16)0.f;
  unsigned* bar = (unsigned*)(ws + OFF_BAR);
  for (size_t j = t; j < 8192; j += st) bar[j] = 0u;
}

// ---------------------------------------------------------------------------
__global__ __launch_bounds__(NT, 1) void gru_main(
    const float* __restrict__ x, const float* __restrict__ b0, const float* __restrict__ b1,
    const float* __restrict__ bp, float* __restrict__ out, char* __restrict__ ws)
{
  extern __shared__ char lds[];

  const f16* WH0Hp = (const f16*)(ws + OFF_WH0H); const f16* WH0Lp = (const f16*)(ws + OFF_WH0L);
  const f16* WI1Hp = (const f16*)(ws + OFF_WI1H); const f16* WI1Lp = (const f16*)(ws + OFF_WI1L);
  const f16* WH1Hp = (const f16*)(ws + OFF_WH1H); const f16* WH1Lp = (const f16*)(ws + OFF_WH1L);
  const f16* WPHp  = (const f16*)(ws + OFF_WPH);
  const f16* WI0Hp = (const f16*)(ws + OFF_WI0H); const f16* WI0Lp = (const f16*)(ws + OFF_WI0L);
  f16* H0H = (f16*)(ws + OFF_H0H);
  f16* H0L = (f16*)(ws + OFF_H0L);
  f16* RH0 = (f16*)(ws + OFF_RH0);
  f16* RH1 = (f16*)(ws + OFF_RH1);
  f16* Z0  = (f16*)(ws + OFF_Z0);
  f16* Z1  = (f16*)(ws + OFF_Z1);
  float* GIN = (float*)(ws + OFF_GIN);
  unsigned* bar = (unsigned*)(ws + OFF_BAR);

  const int bid = blockIdx.x, tid = threadIdx.x;
  const int wid = tid >> 6, lane = tid & 63;
  const int lr = lane & 15, lh = lane >> 4, lkb = lh << 4;
  const int xcd = bid & 7, kk = bid >> 3;

  // phase-A role (XCD-grouped): aid = xcd*28 + kk, kk<28
  const bool hasA = kk < 28;
  const int aid = xcd * 28 + kk;
  const int mgA = hasA ? aid / 112 : 0;
  const int sA = hasA ? aid % 112 : 0;
  const int typeA = sA < 32 ? 0 : (sA < 96 ? 1 : 2);
  const int slotA = typeA == 0 ? sA : (typeA == 1 ? sA - 32 : sA - 96);
  const int m0A = mgA * 256;
  const int wm02 = (wid >> 1) * 128, wn02 = (wid & 1) * 16;
  const int wm1 = wid * 64;

  // phase-B role: pb = xcd*32 + kk
  const int pb = xcd * 32 + kk;
  const int mgB = pb >> 6, sB = pb & 63;
  const bool isN0 = sB < 32;
  const int colB0 = (sB & 31) * 16;
  const int m0B = mgB * 128, wmB = wid * 32;

  char* WXA = lds + LO_WXA; char* WXB = lds + LO_WXB;
  char* S0 = lds + LO_STG0; char* S1 = lds + LO_STG1;
  char* BA = lds + LO_BA; char* BB = lds + LO_BB;

  // ---- one-time: weights -> LDS (persistent across all barriers) ----
  if (hasA) {
    if (typeA == 0) {
      ldB512(BA, 0, WH0Hp, slotA * 32, 32, tid); ldB512(BA, 32, WH0Lp, slotA * 32, 32, tid);
      ldWX(WXA, 0, WI0Hp, slotA * 32, 32, tid);  ldWX(WXA, 32, WI0Lp, slotA * 32, 32, tid);
    } else if (typeA == 1) {
      ldB512(BA, 0, WI1Hp, slotA * 16, 16, tid); ldB512(BA, 16, WI1Lp, slotA * 16, 16, tid);
      ldB512(BA, 32, WH1Hp, slotA * 16, 16, tid); ldB512(BA, 48, WH1Lp, slotA * 16, 16, tid);
    } else {
      ldB512(BA, 0, WI1Hp, 1024 + slotA * 32, 32, tid); ldB512(BA, 32, WI1Lp, 1024 + slotA * 32, 32, tid);
    }
  }
  if (isN0) {
    ldB512(BB, 0, WH0Hp, 1024 + colB0, 16, tid); ldB512(BB, 16, WH0Lp, 1024 + colB0, 16, tid);
    ldWX(WXB, 0, WI0Hp, 1024 + colB0, 16, tid);  ldWX(WXB, 16, WI0Lp, 1024 + colB0, 16, tid);
  } else {
    ldB512(BB, 0, WH1Hp, 1024 + colB0, 16, tid); ldB512(BB, 16, WH1Lp, 1024 + colB0, 16, tid);
  }
  __syncthreads();

  // per-thread constant biases
  float biasA = 0.f;
  if (hasA) {
    if (typeA == 0)      biasA = b0[slotA * 32 + wn02 + lr];
    else if (typeA == 1) biasA = b1[slotA * 16 + lr];
    else                 biasA = b1[1024 + slotA * 32 + wn02 + lr];
  }
  const float biasB = isN0 ? b0[1024 + colB0 + lr] : 0.f;

  unsigned lg = 0;
  for (int i = 0; i <= SEQ; ++i) {
    const int wpar = i & 1;  // H1 write parity this iter; read = opposite
    const f16* H1Hr = (const f16*)(ws + (wpar ? OFF_H1H0 : OFF_H1H1));
    const f16* H1Lr = (const f16*)(ws + (wpar ? OFF_H1L0 : OFF_H1L1));
    f16* H1Hw = (f16*)(ws + (wpar ? OFF_H1H1 : OFF_H1H0));
    f16* H1Lw = (f16*)(ws + (wpar ? OFF_H1L1 : OFF_H1L0));

    // ========================= PHASE A =========================
    if (hasA) {
      if (typeA == 0 && i < SEQ) {
        // preload x slice (hidden under GEMM)
        float4 xr[8];
#pragma unroll
        for (int j = 0; j < 4; ++j) { int idx = tid + j * NT; int r = idx >> 2, g = idx & 3;
          const float* sx = x + (((size_t)(m0A + r)) << 14) + (size_t)i * 32 + g * 8;
          xr[2 * j] = ((const float4*)sx)[0]; xr[2 * j + 1] = ((const float4*)sx)[1]; }
        f32x4 am[8] = {}, ac[8] = {};
        runA<8>(H0H, m0A, lds, wm02, wn02, 32 + wn02, tid, lr, lkb, am, ac);
        // x-fold (K=32, split)
#pragma unroll
        for (int j = 0; j < 4; ++j) { int idx = tid + j * NT; int r = idx >> 2, g = idx & 3;
          union { uint4 u; f16 e[8]; } H, L;
          const float* f0 = (const float*)&xr[2 * j];
          const float* f1 = (const float*)&xr[2 * j + 1];
#pragma unroll
          for (int e = 0; e < 4; ++e) { split2(f0[e], H.e[e], L.e[e]); split2(f1[e], H.e[4 + e], L.e[4 + e]); }
          *(uint4*)(S0 + r * 80 + g * 16) = H.u; *(uint4*)(S1 + r * 80 + g * 16) = L.u; }
        __syncthreads();
        mmX<8>(S0, S1, WXA, wm02, wn02, 32 + wn02, lr, lkb, am, ac);
        // epilogue: r/z gates
        const bool isR = (slotA < 16);
        const int ncol = slotA * 32 + wn02 + lr;
        size_t base = (size_t)(m0A + wm02 + lh * 4) * 512 + ncol;
#pragma unroll
        for (int fm = 0; fm < 8; ++fm)
#pragma unroll
        for (int r4 = 0; r4 < 4; ++r4) {
          size_t off = base + (size_t)(fm * 16 + r4) * 512;
          float s = sigm(am[fm][r4] + ac[fm][r4] * INV_SC + biasA);
          if (isR) {
            float h0v = ld16f(H0H + off) + ld16f(H0L + off) * INV_SC;
            st16(RH0 + off, (f16)(s * h0v));
          } else {
            st16(Z0 + off - 512, (f16)s);
          }
        }
      } else if (typeA == 1 && i >= 1) {
        f32x4 am[4] = {}, ac[4] = {};
        runA1(H0H, H1Hr, m0A, lds, wm1, tid, lr, lkb, am, ac);
        const bool isR = (slotA < 32);
        const int ncol = slotA * 16 + lr;
        size_t base = (size_t)(m0A + wm1 + lh * 4) * 512 + ncol;
#pragma unroll
        for (int fm = 0; fm < 4; ++fm)
#pragma unroll
        for (int r4 = 0; r4 < 4; ++r4) {
          size_t off = base + (size_t)(fm * 16 + r4) * 512;
          float s = sigm(am[fm][r4] + ac[fm][r4] * INV_SC + biasA);
          if (isR) {
            float h1v = ld16f(H1Hr + off) + ld16f(H1Lr + off) * INV_SC;
            st16(RH1 + off, (f16)(s * h1v));
          } else {
            st16(Z1 + off - 512, (f16)s);
          }
        }
      } else if (typeA == 2 && i >= 1) {
        f32x4 am[8] = {}, ac[8] = {};
        runA<8>(H0H, m0A, lds, wm02, wn02, 32 + wn02, tid, lr, lkb, am, ac);
        const int ncol = slotA * 32 + wn02 + lr;
        size_t base = (size_t)(m0A + wm02 + lh * 4) * 512 + ncol;
#pragma unroll
        for (int fm = 0; fm < 8; ++fm)
#pragma unroll
        for (int r4 = 0; r4 < 4; ++r4) {
          size_t off = base + (size_t)(fm * 16 + r4) * 512;
          st32(GIN + off, am[fm][r4] + ac[fm][r4] * INV_SC + biasA);
        }
      }
    }
    ++lg; gbar(bar, bid, tid, lg);

    // ========================= PHASE B =========================
    if (isN0 ? (i < SEQ) : (i >= 1)) {
      f32x4 am[2] = {}, ac[2] = {};
      if (isN0) {
        float4 xr[4];
#pragma unroll
        for (int j = 0; j < 2; ++j) { int idx = tid + j * NT; int r = idx >> 2, g = idx & 3;
          const float* sx = x + (((size_t)(m0B + r)) << 14) + (size_t)i * 32 + g * 8;
          xr[2 * j] = ((const float4*)sx)[0]; xr[2 * j + 1] = ((const float4*)sx)[1]; }
        runB<2>(RH0, m0B, lds, wmB, tid, lr, lkb, am, ac);
#pragma unroll
        for (int j = 0; j < 2; ++j) { int idx = tid + j * NT; int r = idx >> 2, g = idx & 3;
          union { uint4 u; f16 e[8]; } H, L;
          const float* f0 = (const float*)&xr[2 * j];
          const float* f1 = (const float*)&xr[2 * j + 1];
#pragma unroll
          for (int e = 0; e < 4; ++e) { split2(f0[e], H.e[e], L.e[e]); split2(f1[e], H.e[4 + e], L.e[4 + e]); }
          *(uint4*)(S0 + r * 80 + g * 16) = H.u; *(uint4*)(S1 + r * 80 + g * 16) = L.u; }
        __syncthreads();
        mmX<2>(S0, S1, WXB, wmB, 0, 16, lr, lkb, am, ac);
        size_t base = (size_t)(m0B + wmB + lh * 4) * 512 + colB0 + lr;
#pragma unroll
        for (int fm = 0; fm < 2; ++fm)
#pragma unroll
        for (int r4 = 0; r4 < 4; ++r4) {
          size_t off = base + (size_t)(fm * 16 + r4) * 512;
          float nv = tanh_f(am[fm][r4] + ac[fm][r4] * INV_SC + biasB);
          float z = ld16f(Z0 + off);
          float h0v = ld16f(H0H + off) + ld16f(H0L + off) * INV_SC;
          float hn = (1.f - z) * nv + z * h0v;
          f16 hi, lo; split2(hn, hi, lo);
          st16(H0H + off, hi); st16(H0L + off, lo);
        }
      } else {
        runB<2>(RH1, m0B, lds, wmB, tid, lr, lkb, am, ac);
        size_t base = (size_t)(m0B + wmB + lh * 4) * 512 + colB0 + lr;
#pragma unroll
        for (int fm = 0; fm < 2; ++fm)
#pragma unroll
        for (int r4 = 0; r4 < 4; ++r4) {
          size_t off = base + (size_t)(fm * 16 + r4) * 512;
          float nv = tanh_f(am[fm][r4] + ac[fm][r4] * INV_SC + ld32f(GIN + off));
          float z = ld16f(Z1 + off);
          float h1v = ld16f(H1Hr + off) + ld16f(H1Lr + off) * INV_SC;
          float hn = (1.f - z) * nv + z * h1v;
          f16 hi, lo; split2(hn, hi, lo);
          st16(H1Hw + off, hi); st16(H1Lw + off, lo);
        }
      }
    }
    ++lg; gbar(bar, bid, tid, lg);
  }

  // ========================= PROJECTION (single f16) =========================
  {
    const f16* H1p = (const f16*)(ws + OFF_H1H0);   // final h1 (written at i=512, parity 0)
    const int m0 = (bid >> 6) * 128, col0 = (bid & 63) * 48;
    const int wm = wid * 32;
    f32x4 acc[2][3] = {};
#pragma unroll 1
    for (int c = 0; c < 8; ++c) {
      uint4 va[4]; uint4 vb[2];
#pragma unroll
      for (int j = 0; j < 4; ++j) { int idx = tid + j * NT; int r = idx >> 3, g = idx & 7;
        va[j] = *(const uint4*)(H1p + (size_t)(m0 + r) * 512 + c * 64 + g * 8); }
#pragma unroll
      for (int j = 0; j < 2; ++j) { int idx = tid + j * NT;
        if (idx < 384) { int r = idx >> 3, g = idx & 7;
          vb[j] = *(const uint4*)(WPHp + (size_t)(col0 + r) * 512 + c * 64 + g * 8); } }
      __syncthreads();   // prev mfma done reading staging
#pragma unroll
      for (int j = 0; j < 4; ++j) { int idx = tid + j * NT; int r = idx >> 3, g = idx & 7;
        *(uint4*)(S0 + r * 144 + g * 16) = va[j]; }
#pragma unroll
      for (int j = 0; j < 2; ++j) { int idx = tid + j * NT;
        if (idx < 384) { int r = idx >> 3, g = idx & 7;
          *(uint4*)(S1 + r * 144 + g * 16) = vb[j]; } }
      __syncthreads();
#pragma unroll
      for (int ki = 0; ki < 2; ++ki) {
        half8 b[3];
#pragma unroll
        for (int fn = 0; fn < 3; ++fn)
          b[fn] = *(const half8*)(S1 + (fn * 16 + lr) * 144 + ki * 64 + lkb);
#pragma unroll
        for (int fm = 0; fm < 2; ++fm) {
          half8 a = *(const half8*)(S0 + (wm + fm * 16 + lr) * 144 + ki * 64 + lkb);
#pragma unroll
          for (int fn = 0; fn < 3; ++fn) acc[fm][fn] = MFMA16(a, b[fn], acc[fm][fn]);
        }
      }
    }
#pragma unroll
    for (int fm = 0; fm < 2; ++fm)
#pragma unroll
    for (int fn = 0; fn < 3; ++fn)
#pragma unroll
    for (int r4 = 0; r4 < 4; ++r4) {
      int m = m0 + wm + fm * 16 + lh * 4 + r4;
      int nc = col0 + fn * 16 + lr;
      out[(size_t)m * 3072 + nc] = acc[fm][fn][r4] + bp[nc];
    }
  }
}

// ---------------------------------------------------------------------------
extern "C" void kernel_launch(void* const* d_in, const int* in_sizes, int n_in,
                              void* d_out, int out_size, void* d_ws, size_t ws_size,
                              hipStream_t stream) {
  (void)in_sizes; (void)n_in; (void)out_size; (void)ws_size; // needs ws >= ~19.2MB
  const float* x   = (const float*)d_in[0];
  const float* Wi0 = (const float*)d_in[1];
  const float* Wh0 = (const float*)d_in[2];
  const float* b0  = (const float*)d_in[3];
  const float* Wi1 = (const float*)d_in[4];
  const float* Wh1 = (const float*)d_in[5];
  const float* b1  = (const float*)d_in[6];
  const float* Wp  = (const float*)d_in[7];
  const float* bp  = (const float*)d_in[8];
  char* ws = (char*)d_ws;
  static_assert(LDS_BYTES <= 163840, "LDS budget");
  (void)hipFuncSetAttribute(reinterpret_cast<const void*>(gru_main),
                            hipFuncAttributeMaxDynamicSharedMemorySize, LDS_BYTES);
  hipLaunchKernelGGL(gru_setup, dim3(512), dim3(NT), 0, stream, Wi0, Wh0, Wi1, Wh1, Wp, ws);
  hipLaunchKernelGGL(gru_main, dim3(NBLK), dim3(NT), LDS_BYTES, stream,
                     x, b0, b1, bp, (float*)d_out, ws);
}